// Round 7
// baseline (16.331 us; speedup 1.0000x reference)
//
#include <hip/hip_runtime.h>

// out[b,o] = sum_k sbar[b,k] * Meff[k,o]
//   sbar[b,k] = mean_n exp(-(r_bn - 3k/7)^2),  r = ||p - centroid|| (+1e-12 under sqrt)
//   Meff = W1a@W1b@W2a@W2b / sqrt(8*6*6*6), with 1/128 point-mean AND
//   wk = exp(-(3k/7)^2) folded in.  exp(-(r-ck)^2) = wk * e^{-r^2} * (e^{6r/7})^k.
//
// v7: point-per-lane, ideally coalesced, zero data movement.
//   Lane l loads point 3*(base+l) as 3 consecutive floats -> global_load_dwordx3;
//   per instruction the wave covers 768 contiguous bytes (12 lines, 1x line
//   amplification). Batch = 128 points = 2 wave-registers; reductions are
//   full-64-lane (DPP row_ror + ds_swizzle xor16 + shfl xor32; value-split
//   butterfly for the 8 RBF accumulators; readlane -> SGPR for the matvec).
//   Wave = 4 batches (6 KB), all 8 loads issued up-front. 32 waves/CU.

struct __attribute__((packed, aligned(4))) F3 { float x, y, z; };

template <int C>
__device__ __forceinline__ float dppmov(float v) {
    return __int_as_float(__builtin_amdgcn_update_dpp(
        0, __float_as_int(v), C, 0xF, 0xF, true));
}
template <int PAT>
__device__ __forceinline__ float swzf(float v) {
    return __int_as_float(__builtin_amdgcn_ds_swizzle(__float_as_int(v), PAT));
}
__device__ __forceinline__ float rowsum16(float v) {
    v += dppmov<0x121>(v);   // row_ror:1
    v += dppmov<0x122>(v);   // row_ror:2
    v += dppmov<0x124>(v);   // row_ror:4
    v += dppmov<0x128>(v);   // row_ror:8
    return v;
}
__device__ __forceinline__ float wsum64(float v) {
    v = rowsum16(v);
    v += swzf<0x401F>(v);            // xor 16
    v += __shfl_xor(v, 32, 64);      // xor 32
    return v;                         // all 64 lanes hold the total
}
__device__ __forceinline__ float rlane(float v, int k) {
    return __int_as_float(__builtin_amdgcn_readlane(__float_as_int(v), k));
}

__global__ __launch_bounds__(256, 8) void sph_fused(
    const float* __restrict__ pos,
    const float* __restrict__ W1a, const float* __restrict__ W1b,
    const float* __restrict__ W2a, const float* __restrict__ W2b,
    float* __restrict__ out, int nBatch)
{
    __shared__ float BBs[36];
    __shared__ float CCs[36];
    __shared__ float MMs[48];

    const int t = threadIdx.x;

    // ---- effective 8x6 matrix, wk folded into row k (tiny, once per block) ----
    if (t < 36) {
        const int c = t / 6, o = t - 6 * c;
        float s = 0.f;
        #pragma unroll
        for (int j = 0; j < 6; ++j) s += W2a[c * 6 + j] * W2b[j * 6 + o];
        BBs[t] = s;
    }
    __syncthreads();
    if (t < 36) {
        const int c = t / 6, o = t - 6 * c;
        float s = 0.f;
        #pragma unroll
        for (int j = 0; j < 6; ++j) s += W1b[c * 6 + j] * BBs[j * 6 + o];
        CCs[t] = s;
    }
    __syncthreads();
    if (t < 48) {
        const int k = t / 6, o = t - 6 * k;
        float s = 0.f;
        #pragma unroll
        for (int c = 0; c < 6; ++c) s += W1a[k * 6 + c] * CCs[c * 6 + o];
        const float WKtab[8] = {1.0f, 0.83220583f, 0.47965235f, 0.19146295f,
                                0.05293049f, 0.01013418f, 0.00134381f, 1.2340980e-4f};
        MMs[t] = s * WKtab[k] * (0.024056261216234408f / 128.0f); // 1/sqrt(1728)/128
    }
    __syncthreads();   // last block-wide barrier before any early return

    const int lane = t & 63;
    const int w    = t >> 6;

    const int nTiles = (nBatch + 3) >> 2;        // 4 batches per wave-tile
    const int tile = blockIdx.x * 4 + w;
    if (tile >= nTiles) return;

    // ---- per-lane copy of Meff column for this lane's (batch,col) slot ----
    const int qsel = lane / 6;                   // which batch this lane stores (if <4)
    const int col  = (lane < 24) ? (lane - 6 * qsel) : 0;
    float Mc[8];
    #pragma unroll
    for (int k = 0; k < 8; ++k) Mc[k] = MMs[k * 6 + col];

    // ---- load 8 points (4 batches x 2 per lane), fully coalesced dwordx3 ----
    const int maxPt = nBatch * 128 - 1;
    float px[8], py[8], pz[8];
    #pragma unroll
    for (int s = 0; s < 8; ++s) {
        int pt = tile * 512 + s * 64 + lane;     // s = 2q + half
        if (pt > maxPt) pt = maxPt;              // tail clamp; stores guarded
        const F3 v = *reinterpret_cast<const F3*>(pos + 3 * (size_t)pt);
        px[s] = v.x; py[s] = v.y; pz[s] = v.z;
    }

    float ov = 0.f;                              // this lane's output (lanes 0..23)

    #pragma unroll
    for (int q = 0; q < 4; ++q) {
        const int k0 = 2 * q, k1 = 2 * q + 1;

        // centroid of the 128-point batch (full-wave reduction, broadcast)
        const float mx = wsum64(px[k0] + px[k1]) * (1.f / 128.f);
        const float my = wsum64(py[k0] + py[k1]) * (1.f / 128.f);
        const float mz = wsum64(pz[k0] + pz[k1]) * (1.f / 128.f);

        // RBFs for this lane's 2 points: 2 exps + 1 sqrt each
        float a0 = 0.f, a1 = 0.f, a2 = 0.f, a3 = 0.f,
              a4 = 0.f, a5 = 0.f, a6 = 0.f, a7 = 0.f;
        #pragma unroll
        for (int h = 0; h < 2; ++h) {
            const int s = 2 * q + h;
            const float dx = px[s] - mx;
            const float dy = py[s] - my;
            const float dz = pz[s] - mz;
            const float r2 = fmaf(dx, dx, fmaf(dy, dy, fmaf(dz, dz, 1e-12f)));
            float r;
            asm("v_sqrt_f32 %0, %1" : "=v"(r) : "v"(r2));
            const float E0 = __expf(-r2);                 // e^{-r^2}
            const float Bf = __expf(r * (6.0f / 7.0f));   // e^{6r/7}
            float p = E0;
            a0 += E0;
            p *= Bf; a1 += p;
            p *= Bf; a2 += p;
            p *= Bf; a3 += p;
            p *= Bf; a4 += p;
            p *= Bf; a5 += p;
            p *= Bf; a6 += p;
            p *= Bf; a7 += p;
        }

        // 8-value full-wave sum: value-split butterfly (R1-verified identity
        // mapping) for xor 1/2/4, then plain xor 8/16/32 adds.
        const int l0 = lane & 1, l1 = (lane >> 1) & 1, l2 = (lane >> 2) & 1;
        float b0, b1, b2, b3;
        {
            const float s0 = l0 ? a0 : a1, k0_ = l0 ? a1 : a0;
            const float s1 = l0 ? a2 : a3, k1_ = l0 ? a3 : a2;
            const float s2 = l0 ? a4 : a5, k2_ = l0 ? a5 : a4;
            const float s3 = l0 ? a6 : a7, k3_ = l0 ? a7 : a6;
            b0 = k0_ + __shfl_xor(s0, 1, 64);
            b1 = k1_ + __shfl_xor(s1, 1, 64);
            b2 = k2_ + __shfl_xor(s2, 1, 64);
            b3 = k3_ + __shfl_xor(s3, 1, 64);
        }
        float c0, c1;
        {
            const float s0 = l1 ? b0 : b1, k0_ = l1 ? b1 : b0;
            const float s1 = l1 ? b2 : b3, k1_ = l1 ? b3 : b2;
            c0 = k0_ + __shfl_xor(s0, 2, 64);
            c1 = k1_ + __shfl_xor(s1, 2, 64);
        }
        float S;
        {
            const float s0 = l2 ? c0 : c1, k0_ = l2 ? c1 : c0;
            S = k0_ + __shfl_xor(s0, 4, 64);
        }
        S += __shfl_xor(S, 8, 64);
        S += __shfl_xor(S, 16, 64);
        S += __shfl_xor(S, 32, 64);
        // every lane now holds the batch-total of acc[lane & 7]

        // broadcast the 8 totals to SGPRs; 8x6 matvec for this lane's column
        float o_ = rlane(S, 0) * Mc[0];
        o_ = fmaf(rlane(S, 1), Mc[1], o_);
        o_ = fmaf(rlane(S, 2), Mc[2], o_);
        o_ = fmaf(rlane(S, 3), Mc[3], o_);
        o_ = fmaf(rlane(S, 4), Mc[4], o_);
        o_ = fmaf(rlane(S, 5), Mc[5], o_);
        o_ = fmaf(rlane(S, 6), Mc[6], o_);
        o_ = fmaf(rlane(S, 7), Mc[7], o_);

        ov = (qsel == q) ? o_ : ov;              // keep in lanes 6q..6q+5
    }

    // one contiguous 96 B store per wave: lanes 0..23
    const int batch = tile * 4 + qsel;
    if (lane < 24 && batch < nBatch)
        out[(size_t)tile * 24 + lane] = ov;
}

extern "C" void kernel_launch(void* const* d_in, const int* in_sizes, int n_in,
                              void* d_out, int out_size, void* d_ws, size_t ws_size,
                              hipStream_t stream) {
    const float* pos = (const float*)d_in[0];
    const float* W1a = (const float*)d_in[1];
    const float* W1b = (const float*)d_in[2];
    const float* W2a = (const float*)d_in[5];
    const float* W2b = (const float*)d_in[6];
    float* out = (float*)d_out;

    const int nBatch = in_sizes[0] / 384;        // 32768 for the bench shape
    const int nTiles = (nBatch + 3) / 4;         // 4 batches per wave
    const int grid = (nTiles + 3) / 4;           // 4 waves per block

    sph_fused<<<dim3(grid), dim3(256), 0, stream>>>(pos, W1a, W1b, W2a, W2b, out, nBatch);
}

// Round 8
// 15.026 us; speedup vs baseline: 1.0868x; 1.0868x over previous
//
#include <hip/hip_runtime.h>

// out[b,o] = sum_k sbar[b,k] * Meff[k,o]
//   sbar[b,k] = mean_n exp(-(r_bn - 3k/7)^2),  r = ||p - centroid|| (+1e-12 under sqrt)
//   Meff = W1a@W1b@W2a@W2b / sqrt(8*6*6*6), with 1/128 point-mean AND
//   wk = exp(-(3k/7)^2) folded in.  exp(-(r-ck)^2) = wk * e^{-r^2} * (e^{6r/7})^k.
//
// v8 = R5 compute structure (batch per 16-lane row, 8 pts/lane, DPP-only
// reductions, ZERO DS ops in the hot path) with ONE change: load addressing.
//   R5:  lane owns contiguous 96 B  -> each instr touches 64 cache lines (4x
//        L1-probe amplification).
//   v8:  pt = q*16 + lsub (row-interleaved) -> each instr is 4 contiguous
//        192 B runs = 12 lines, fully covered. Clean A/B on line amplification.
// 32 waves/CU (__launch_bounds__(256,8)), one 6 KB tile (4 batches) per wave.

struct __attribute__((packed, aligned(4))) F3 { float x, y, z; };

template <int N>
__device__ __forceinline__ float ror16(float v) {
    // v_mov_b32_dpp row_ror:N (rotate within each 16-lane row)
    return __int_as_float(__builtin_amdgcn_update_dpp(
        0, __float_as_int(v), 0x120 | N, 0xF, 0xF, true));
}
__device__ __forceinline__ float rowsum16(float v) {
    v += ror16<1>(v);
    v += ror16<2>(v);
    v += ror16<4>(v);
    v += ror16<8>(v);
    return v;   // all 16 lanes of the row hold the row total
}

__global__ __launch_bounds__(256, 8) void sph_fused(
    const float* __restrict__ pos,
    const float* __restrict__ W1a, const float* __restrict__ W1b,
    const float* __restrict__ W2a, const float* __restrict__ W2b,
    float* __restrict__ out, int nBatch)
{
    __shared__ float BBs[36];
    __shared__ float CCs[36];
    __shared__ float MMs[48];

    const int t = threadIdx.x;

    // ---- effective 8x6 matrix, wk folded into row k (tiny, once per block) ----
    if (t < 36) {
        const int c = t / 6, o = t - 6 * c;
        float s = 0.f;
        #pragma unroll
        for (int j = 0; j < 6; ++j) s += W2a[c * 6 + j] * W2b[j * 6 + o];
        BBs[t] = s;
    }
    __syncthreads();
    if (t < 36) {
        const int c = t / 6, o = t - 6 * c;
        float s = 0.f;
        #pragma unroll
        for (int j = 0; j < 6; ++j) s += W1b[c * 6 + j] * BBs[j * 6 + o];
        CCs[t] = s;
    }
    __syncthreads();
    if (t < 48) {
        const int k = t / 6, o = t - 6 * k;
        float s = 0.f;
        #pragma unroll
        for (int c = 0; c < 6; ++c) s += W1a[k * 6 + c] * CCs[c * 6 + o];
        const float WKtab[8] = {1.0f, 0.83220583f, 0.47965235f, 0.19146295f,
                                0.05293049f, 0.01013418f, 0.00134381f, 1.2340980e-4f};
        MMs[t] = s * WKtab[k] * (0.024056261216234408f / 128.0f); // 1/sqrt(1728)/128
    }
    __syncthreads();   // last block-wide barrier before any early return

    const int lane = t & 63;
    const int w    = t >> 6;
    const int lsub = lane & 15;          // lane within 16-lane batch row
    const int grp  = lane >> 4;          // batch row within wave (0..3)

    const int nTiles = (nBatch + 3) >> 2;        // 4 batches per wave-tile
    const int tile = blockIdx.x * 4 + w;
    if (tile >= nTiles) return;

    const int batch = tile * 4 + grp;

    // ---- 8 row-interleaved dwordx3 loads: instr q = 4 contiguous 192 B runs ----
    const int maxPt = nBatch * 128 - 1;
    float px[8], py[8], pz[8];
    #pragma unroll
    for (int q = 0; q < 8; ++q) {
        int pt = batch * 128 + q * 16 + lsub;    // within-batch point q*16+lsub
        if (pt > maxPt) pt = maxPt;              // tail clamp; stores guarded
        const F3 v = *reinterpret_cast<const F3*>(pos + 3 * pt);
        px[q] = v.x; py[q] = v.y; pz[q] = v.z;
    }

    // ---- centroid over the 16-lane batch row (DPP only) ----
    float sx = 0.f, sy = 0.f, sz = 0.f;
    #pragma unroll
    for (int q = 0; q < 8; ++q) { sx += px[q]; sy += py[q]; sz += pz[q]; }
    sx = rowsum16(sx); sy = rowsum16(sy); sz = rowsum16(sz);
    const float mx = sx * (1.f / 128.f), my = sy * (1.f / 128.f), mz = sz * (1.f / 128.f);

    // ---- RBFs: 2 exps + 1 sqrt per point; wk deferred to the matrix ----
    float a0 = 0.f, a1 = 0.f, a2 = 0.f, a3 = 0.f,
          a4 = 0.f, a5 = 0.f, a6 = 0.f, a7 = 0.f;
    #pragma unroll
    for (int q = 0; q < 8; ++q) {
        const float dx = px[q] - mx;
        const float dy = py[q] - my;
        const float dz = pz[q] - mz;
        const float r2 = fmaf(dx, dx, fmaf(dy, dy, fmaf(dz, dz, 1e-12f)));
        float r;
        asm("v_sqrt_f32 %0, %1" : "=v"(r) : "v"(r2));
        const float E0 = __expf(-r2);                 // e^{-r^2}
        const float Bf = __expf(r * (6.0f / 7.0f));   // e^{6r/7}
        float p = E0;
        a0 += E0;
        p *= Bf; a1 += p;
        p *= Bf; a2 += p;
        p *= Bf; a3 += p;
        p *= Bf; a4 += p;
        p *= Bf; a5 += p;
        p *= Bf; a6 += p;
        p *= Bf; a7 += p;
    }
    a0 = rowsum16(a0); a1 = rowsum16(a1); a2 = rowsum16(a2); a3 = rowsum16(a3);
    a4 = rowsum16(a4); a5 = rowsum16(a5); a6 = rowsum16(a6); a7 = rowsum16(a7);

    // ---- 8x6 matvec: Mcol read from LDS now (point regs dead) ----
    const int col = (lsub < 6) ? lsub : 0;
    float o_ = a0 * MMs[0 * 6 + col];
    o_ = fmaf(a1, MMs[1 * 6 + col], o_);
    o_ = fmaf(a2, MMs[2 * 6 + col], o_);
    o_ = fmaf(a3, MMs[3 * 6 + col], o_);
    o_ = fmaf(a4, MMs[4 * 6 + col], o_);
    o_ = fmaf(a5, MMs[5 * 6 + col], o_);
    o_ = fmaf(a6, MMs[6 * 6 + col], o_);
    o_ = fmaf(a7, MMs[7 * 6 + col], o_);

    if (lsub < 6 && batch < nBatch) out[batch * 6 + lsub] = o_;
}

extern "C" void kernel_launch(void* const* d_in, const int* in_sizes, int n_in,
                              void* d_out, int out_size, void* d_ws, size_t ws_size,
                              hipStream_t stream) {
    const float* pos = (const float*)d_in[0];
    const float* W1a = (const float*)d_in[1];
    const float* W1b = (const float*)d_in[2];
    const float* W2a = (const float*)d_in[5];
    const float* W2b = (const float*)d_in[6];
    float* out = (float*)d_out;

    const int nBatch = in_sizes[0] / 384;        // 32768 for the bench shape
    const int nTiles = (nBatch + 3) / 4;         // 4 batches per wave
    const int grid = (nTiles + 3) / 4;           // 4 waves per block

    sph_fused<<<dim3(grid), dim3(256), 0, stream>>>(pos, W1a, W1b, W2a, W2b, out, nBatch);
}